// Round 14
// baseline (111.585 us; speedup 1.0000x reference)
//
#include <hip/hip_runtime.h>

// ---------------------------------------------------------------------------
// ModernBertAttention: x[4,2048,768] -> QKV gemm(+RoPE) -> sliding-window
// MFMA attention (window=64) -> out-proj gemm.  out f32 [4,2048,768].
// ---------------------------------------------------------------------------

typedef __attribute__((ext_vector_type(8))) _Float16 f16x8;
typedef __attribute__((ext_vector_type(4))) float    f32x4;

#define BDIM 4
#define SDIM 2048
#define HDIM 768
#define NH   12
#define HD   64
#define NQKV 2304   // 3*HDIM
#define MROWS 8192  // B*S

#define MFMA16(a, b, c) __builtin_amdgcn_mfma_f32_16x16x32_f16(a, b, c, 0, 0, 0)

// ---------------------------------------------------------------------------
__device__ __forceinline__ void gload16(const void* g, void* l) {
    __builtin_amdgcn_global_load_lds(
        (__attribute__((address_space(1))) void*)(g),
        (__attribute__((address_space(3))) void*)(l),
        16, 0, 0);
}

// --------------------- f32 -> f16 convert (x + weights) ---------------------
__global__ __launch_bounds__(256) void cvt_all(
    const float* __restrict__ x,    _Float16* __restrict__ dx,
    const float* __restrict__ wqkv, _Float16* __restrict__ dq,
    const float* __restrict__ wo,   _Float16* __restrict__ dwo)
{
    const int n0 = MROWS * HDIM / 8;  // 786432
    const int n1 = NQKV * HDIM / 8;   // 221184
    const int n2 = HDIM * HDIM / 8;   //  73728
    int i = blockIdx.x * 256 + threadIdx.x;
    const float* s; _Float16* d; int j;
    if (i < n0)                 { s = x;    d = dx;  j = i; }
    else if (i < n0 + n1)       { s = wqkv; d = dq;  j = i - n0; }
    else if (i < n0 + n1 + n2)  { s = wo;   d = dwo; j = i - n0 - n1; }
    else return;
    const float4* s4 = (const float4*)s + (long)j * 2;
    float4 a = s4[0], b = s4[1];
    f16x8 o;
    o[0] = (_Float16)a.x; o[1] = (_Float16)a.y;
    o[2] = (_Float16)a.z; o[3] = (_Float16)a.w;
    o[4] = (_Float16)b.x; o[5] = (_Float16)b.y;
    o[6] = (_Float16)b.z; o[7] = (_Float16)b.w;
    *((f16x8*)d + j) = o;
}

// -------- QKV GEMM: 256x128 tile, 8 waves, triple-buffer counted-vmcnt ------
// Config rationale (R11/R12 post-mortem): need big tile (less LDS+L2 traffic
// per FLOP) AND multi-block residency (latency cover) AND smooth grid.
// 256x128, BK=32, 8 waves (4M x 2N, wave-tile 64x64): LDS 3x24KB = 72KB ->
// 2 blocks/CU = 16 waves/CU (4/SIMD, best coverage yet); grid 576 = 2.25
// rounds (11% tail vs 44% at 288). Engine = R12's proven triple-buffer:
// stage t+2 during t, boundary wait vmcnt(3) (t+1 resident, t+2 in flight),
// one raw s_barrier per tile. Swizzle: phys_granule = logical ^ ((row>>1)&3).
// Epilogue: RoPE q/k + scatter q/k/v (f16) to [B,nh,S,hd].
__global__ __launch_bounds__(512) void gemm_qkv_w8(
    const _Float16* __restrict__ A,     // xh
    const _Float16* __restrict__ Bt,    // wqkvh
    const float* __restrict__ cosp,
    const float* __restrict__ sinp,
    _Float16* __restrict__ qh,
    _Float16* __restrict__ kh,
    _Float16* __restrict__ vh)
{
    const int K = HDIM;
    __shared__ __align__(16) _Float16 lsA[3][256 * 32];   // 16KB each
    __shared__ __align__(16) _Float16 lsB[3][128 * 32];   //  8KB each

    const int nTn = NQKV >> 7;                // 18
    int nwg = gridDim.x;                      // 576
    int bid = blockIdx.x;
    int cpx = nwg >> 3;                       // 72
    int wg  = (bid & 7) * cpx + (bid >> 3);   // XCD-aware bijective swizzle
    int tm = wg / nTn, tn = wg % nTn;
    int m0 = tm << 8, n0 = tn << 7;

    int tid  = threadIdx.x;
    int lane = tid & 63;
    int w    = tid >> 6;
    int wr   = w >> 1, wc = w & 1;            // wave grid 4M x 2N
    int l15  = lane & 15, lk = lane >> 4;

    f32x4 acc[4][4] = {};

    // staging: 512 threads; A rows tid>>2 (0..127) and +128 (2 loads);
    // B rows tid>>2 (1 load). Source granule pre-swizzled.
    int srow = tid >> 2;                      // 0..127
    int lg   = (tid & 3) ^ ((tid >> 3) & 3);
    const _Float16* gA = A  + (long)(m0 + srow) * K + lg * 8;
    const _Float16* gB = Bt + (long)(n0 + srow) * K + lg * 8;

    auto STAGE = [&](int buf, int t) {        // 3 loads/thread/tile
        gload16(gA + t * 32,             &lsA[buf][tid * 8]);
        gload16(gA + t * 32 + 128L * K,  &lsA[buf][tid * 8 + 4096]);
        gload16(gB + t * 32,             &lsB[buf][tid * 8]);
    };
    auto RD = [&](const _Float16* base, int rbase, int f) -> f16x8 {
        int r = rbase + f * 16 + l15;
        int pg = lk ^ ((r >> 1) & 3);
        return *(const f16x8*)&base[r * 32 + pg * 8];
    };

    const int NT = K >> 5;   // 24

    STAGE(0, 0);
    STAGE(1, 1);
    asm volatile("s_waitcnt vmcnt(3)" ::: "memory");   // tile 0 resident
    __builtin_amdgcn_s_barrier();

    int cur = 0;
    for (int t = 0; t < NT; ++t) {
        const _Float16* aC = lsA[cur];
        const _Float16* bC = lsB[cur];
        int stg = cur + 2; if (stg >= 3) stg -= 3;

        f16x8 af[4], bf[4];
#pragma unroll
        for (int mf = 0; mf < 4; ++mf) af[mf] = RD(aC, wr * 64, mf);
#pragma unroll
        for (int nf = 0; nf < 4; ++nf) bf[nf] = RD(bC, wc * 64, nf);
        if (t + 2 < NT) STAGE(stg, t + 2);

        __builtin_amdgcn_s_setprio(1);
#pragma unroll
        for (int mf = 0; mf < 4; ++mf)
#pragma unroll
            for (int nf = 0; nf < 4; ++nf)
                acc[mf][nf] = MFMA16(af[mf], bf[nf], acc[mf][nf]);
        __builtin_amdgcn_s_setprio(0);

        if (t + 1 < NT) {
            if (t + 2 < NT)
                asm volatile("s_waitcnt vmcnt(3)" ::: "memory"); // t+1 resident
            else
                asm volatile("s_waitcnt vmcnt(0)" ::: "memory");
            __builtin_amdgcn_s_barrier();
        }
        cur = cur + 1; if (cur == 3) cur = 0;
    }

    // ---- epilogue: RoPE + scatter ----
    int ht = tn * 2 + wc;          // [0,36): t*12 + h
    int tq = ht / NH;
    int h  = ht - tq * NH;
    int b  = m0 >> 11;             // 256-row tile never straddles a batch
    long base_bh = ((long)(b * NH + h)) * SDIM;
#pragma unroll
    for (int mf = 0; mf < 4; ++mf) {
#pragma unroll
        for (int j = 0; j < 4; ++j) {
            int gr = m0 + wr * 64 + mf * 16 + lk * 4 + j;
            int s  = gr & (SDIM - 1);
            if (tq == 2) {
#pragma unroll
                for (int nf = 0; nf < 4; ++nf) {
                    int d = nf * 16 + l15;
                    vh[(base_bh + s) * HD + d] = (_Float16)acc[mf][nf][j];
                }
            } else {
                float vals[4];
#pragma unroll
                for (int nf = 0; nf < 4; ++nf) vals[nf] = acc[mf][nf][j];
#pragma unroll
                for (int nf = 0; nf < 4; ++nf) {
                    int d = nf * 16 + l15;
                    float cc = cosp[(long)gr * HD + d];
                    float ss = sinp[(long)gr * HD + d];
                    float pv = (nf < 2) ? -vals[nf + 2] : vals[nf - 2];
                    float o  = vals[nf] * cc + pv * ss;
                    long oidx = (base_bh + s) * HD + d;
                    if (tq == 0) qh[oidx] = (_Float16)o;
                    else         kh[oidx] = (_Float16)o;
                }
            }
        }
    }
}

// --------------- out-proj GEMM: R12 kernel (verified best) ------------------
__global__ __launch_bounds__(256) void gemm_op8(
    const _Float16* __restrict__ A,
    const _Float16* __restrict__ Bt,
    float* __restrict__ C,
    int M, int N, int K)
{
    __shared__ __align__(16) _Float16 lsA[3][128 * 32];
    __shared__ __align__(16) _Float16 lsB[3][128 * 32];

    int nTn = N >> 7;
    int nwg = gridDim.x;
    int bid = blockIdx.x;
    int cpx = nwg >> 3;
    int wg  = (bid & 7) * cpx + (bid >> 3);
    int tm = wg / nTn, tn = wg % nTn;
    int m0 = tm << 7, n0 = tn << 7;

    int tid  = threadIdx.x;
    int lane = tid & 63;
    int w    = tid >> 6;
    int wr   = w >> 1, wc = w & 1;
    int l15  = lane & 15, lk = lane >> 4;

    f32x4 acc[4][4] = {};

    int srow = tid >> 2;
    int lg   = (tid & 3) ^ ((tid >> 3) & 3);
    const _Float16* gA = A  + (long)(m0 + srow) * K + lg * 8;
    const _Float16* gB = Bt + (long)(n0 + srow) * K + lg * 8;

    auto STAGE = [&](int buf, int t) {
        gload16(gA + t * 32,            &lsA[buf][tid * 8]);
        gload16(gA + t * 32 + 64L * K,  &lsA[buf][tid * 8 + 2048]);
        gload16(gB + t * 32,            &lsB[buf][tid * 8]);
        gload16(gB + t * 32 + 64L * K,  &lsB[buf][tid * 8 + 2048]);
    };
    auto RD = [&](const _Float16* base, int rbase, int f) -> f16x8 {
        int r = rbase + f * 16 + l15;
        int pg = lk ^ ((r >> 1) & 3);
        return *(const f16x8*)&base[r * 32 + pg * 8];
    };

    const int NT = K >> 5;   // 24

    STAGE(0, 0);
    STAGE(1, 1);
    asm volatile("s_waitcnt vmcnt(4)" ::: "memory");
    __builtin_amdgcn_s_barrier();

    int cur = 0;
    for (int t = 0; t < NT; ++t) {
        const _Float16* aC = lsA[cur];
        const _Float16* bC = lsB[cur];
        int stg = cur + 2; if (stg >= 3) stg -= 3;

        f16x8 af[4], bf[4];
#pragma unroll
        for (int mf = 0; mf < 4; ++mf) af[mf] = RD(aC, wr * 64, mf);
#pragma unroll
        for (int nf = 0; nf < 4; ++nf) bf[nf] = RD(bC, wc * 64, nf);
        if (t + 2 < NT) STAGE(stg, t + 2);

        __builtin_amdgcn_s_setprio(1);
#pragma unroll
        for (int mf = 0; mf < 4; ++mf)
#pragma unroll
            for (int nf = 0; nf < 4; ++nf)
                acc[mf][nf] = MFMA16(af[mf], bf[nf], acc[mf][nf]);
        __builtin_amdgcn_s_setprio(0);

        if (t + 1 < NT) {
            if (t + 2 < NT)
                asm volatile("s_waitcnt vmcnt(4)" ::: "memory");
            else
                asm volatile("s_waitcnt vmcnt(0)" ::: "memory");
            __builtin_amdgcn_s_barrier();
        }
        cur = cur + 1; if (cur == 3) cur = 0;
    }

#pragma unroll
    for (int mf = 0; mf < 4; ++mf)
#pragma unroll
        for (int nf = 0; nf < 4; ++nf)
#pragma unroll
            for (int j = 0; j < 4; ++j) {
                int gr = m0 + wr * 64 + mf * 16 + lk * 4 + j;
                int gc = n0 + wc * 64 + nf * 16 + l15;
                C[(long)gr * N + gc] = acc[mf][nf][j];
            }
}

// ---------------------------- MFMA attention --------------------------------
// Block = 4 waves = one (b,h, 64-query tile); key window = 192 keys.
#define SSTR 200
#define PSTR 200
__global__ __launch_bounds__(256) void attn_mfma(
    const _Float16* __restrict__ qh,
    const _Float16* __restrict__ kh,
    const _Float16* __restrict__ vh,
    _Float16* __restrict__ yh)
{
    __shared__ __align__(16) _Float16 lsVT[64 * SSTR];
    __shared__ __align__(16) _Float16 lsP [64 * PSTR];

    int bid = blockIdx.x;
    int qt  = bid & 31;
    int bh  = bid >> 5;
    int q0  = qt << 6;
    int k0  = q0 - 64;
    int tid = threadIdx.x;
    int lane = tid & 63;
    int w = tid >> 6;
    int l15 = lane & 15, lg = lane >> 4;

    const _Float16* Qb = qh + (long)bh * SDIM * HD;
    const _Float16* Kb = kh + (long)bh * SDIM * HD;
    const _Float16* Vb = vh + (long)bh * SDIM * HD;

#pragma unroll
    for (int c = 0; c < 3; ++c) {
        int rk = c * 64 + lane;
        int s  = k0 + rk;
        s = s < 0 ? 0 : (s >= SDIM ? SDIM - 1 : s);
        const f16x8* vr = (const f16x8*)(Vb + (long)s * HD + w * 16);
        f16x8 v0 = vr[0], v1 = vr[1];
#pragma unroll
        for (int e = 0; e < 8; ++e) {
            lsVT[(w * 16 + e)     * SSTR + rk] = v0[e];
            lsVT[(w * 16 + 8 + e) * SSTR + rk] = v1[e];
        }
    }

    int qrow = q0 + w * 16 + l15;
    const f16x8* qp = (const f16x8*)(Qb + (long)qrow * HD + lg * 8);
    f16x8 qa0 = qp[0];
    f16x8 qa1 = qp[4];

    float sums[4] = {0.f, 0.f, 0.f, 0.f};
    int iqb = w * 16 + lg * 4;
#pragma unroll 4
    for (int kt = 0; kt < 12; ++kt) {
        int krow = k0 + kt * 16 + l15;
        int kcl = krow < 0 ? 0 : (krow >= SDIM ? SDIM - 1 : krow);
        const f16x8* kp = (const f16x8*)(Kb + (long)kcl * HD + lg * 8);
        f16x8 kb0 = kp[0], kb1 = kp[4];
        f32x4 acc = {0.f, 0.f, 0.f, 0.f};
        acc = MFMA16(qa0, kb0, acc);
        acc = MFMA16(qa1, kb1, acc);
        int jk = kt * 16 + l15;
        bool kin = (krow >= 0) && (krow < SDIM);
#pragma unroll
        for (int j = 0; j < 4; ++j) {
            int i = iqb + j;
            bool valid = kin && (jk >= i) && (jk <= i + 128);
            float p = valid ? __expf(acc[j] * 0.125f) : 0.f;
            sums[j] += p;
            lsP[(w * 16 + lg * 4 + j) * PSTR + jk] = (_Float16)p;
        }
    }

#pragma unroll
    for (int m = 1; m < 16; m <<= 1) {
#pragma unroll
        for (int j = 0; j < 4; ++j)
            sums[j] += __shfl_xor(sums[j], m, 64);
    }
    float inv[4];
#pragma unroll
    for (int j = 0; j < 4; ++j) inv[j] = 1.f / sums[j];

    __syncthreads();

    f32x4 accy[4] = {};
    const _Float16* prow = &lsP[(w * 16 + l15) * PSTR + lg * 8];
#pragma unroll
    for (int kc = 0; kc < 6; ++kc) {
        f16x8 pa = *(const f16x8*)(prow + kc * 32);
#pragma unroll
        for (int dt = 0; dt < 4; ++dt) {
            f16x8 vb = *(const f16x8*)&lsVT[(dt * 16 + l15) * SSTR + kc * 32 + lg * 8];
            accy[dt] = MFMA16(pa, vb, accy[dt]);
        }
    }

    int b = bh / NH, h = bh - (bh / NH) * NH;
    long outbase = ((long)b * SDIM) * HDIM + (long)h * HD;
#pragma unroll
    for (int dt = 0; dt < 4; ++dt) {
#pragma unroll
        for (int j = 0; j < 4; ++j) {
            int srow = q0 + w * 16 + lg * 4 + j;
            yh[outbase + (long)srow * HDIM + dt * 16 + l15] =
                (_Float16)(accy[dt][j] * inv[j]);
        }
    }
}

// ---------------------------------------------------------------------------
extern "C" void kernel_launch(void* const* d_in, const int* in_sizes, int n_in,
                              void* d_out, int out_size, void* d_ws, size_t ws_size,
                              hipStream_t stream)
{
    const float* x    = (const float*)d_in[0];
    const float* cosp = (const float*)d_in[1];
    const float* sinp = (const float*)d_in[2];
    const float* Wqkv = (const float*)d_in[3];
    const float* Wo   = (const float*)d_in[4];
    float* out = (float*)d_out;

    char* ws = (char*)d_ws;
    _Float16* xh    = (_Float16*)(ws);                    // 12,582,912
    _Float16* wqkvh = (_Float16*)(ws + 12582912);         //  3,538,944
    _Float16* woh   = (_Float16*)(ws + 16121856);         //  1,179,648
    _Float16* qh    = (_Float16*)(ws + 17301504);         // 12,582,912
    _Float16* kh    = (_Float16*)(ws + 29884416);         // 12,582,912
    _Float16* vh    = (_Float16*)(ws + 42467328);         // 12,582,912
    _Float16* yh    = (_Float16*)(ws + 55050240);         // 12,582,912 -> 67,633,152

    // 1) convert x + weights to f16 (single kernel)
    {
        int nthr = MROWS * HDIM / 8 + NQKV * HDIM / 8 + HDIM * HDIM / 8;
        cvt_all<<<(nthr + 255) / 256, 256, 0, stream>>>(x, xh, Wqkv, wqkvh, Wo, woh);
    }

    // 2) QKV gemm: 256x128, 8 waves, 2 blocks/CU, counted-vmcnt triple-buffer
    {
        dim3 grid((MROWS / 256) * (NQKV / 128));   // 32*18 = 576
        gemm_qkv_w8<<<grid, 512, 0, stream>>>(xh, wqkvh, cosp, sinp, qh, kh, vh);
    }

    // 3) sliding-window MFMA attention
    {
        dim3 grid(BDIM * NH * (SDIM / 64));        // 1536
        attn_mfma<<<grid, 256, 0, stream>>>(qh, kh, vh, yh);
    }

    // 4) output projection (R12 kernel)
    {
        dim3 grid((MROWS / 128) * (HDIM / 128));   // 384
        gemm_op8<<<grid, 256, 0, stream>>>(yh, woh, out, MROWS, HDIM, HDIM);
    }
}

// Round 15
// 104.736 us; speedup vs baseline: 1.0654x; 1.0654x over previous
//
#include <hip/hip_runtime.h>

// ---------------------------------------------------------------------------
// ModernBertAttention: x[4,2048,768] -> QKV gemm(+RoPE) -> sliding-window
// MFMA attention (window=64) -> out-proj gemm.  out f32 [4,2048,768].
// Base = R12 (measured best 106.2us). Change: compact [S,32] f32 RoPE tables
// (extracted in cvt_all from the b=0 plane -- bit-identical values) replace
// the [B,S,64] input tables in the QKV epilogue: 16MB poorly-cached table
// traffic -> 512KB L2-resident.
// ---------------------------------------------------------------------------

typedef __attribute__((ext_vector_type(8))) _Float16 f16x8;
typedef __attribute__((ext_vector_type(4))) float    f32x4;

#define BDIM 4
#define SDIM 2048
#define HDIM 768
#define NH   12
#define HD   64
#define NQKV 2304   // 3*HDIM
#define MROWS 8192  // B*S

#define MFMA16(a, b, c) __builtin_amdgcn_mfma_f32_16x16x32_f16(a, b, c, 0, 0, 0)

// ---------------------------------------------------------------------------
__device__ __forceinline__ void gload16(const void* g, void* l) {
    __builtin_amdgcn_global_load_lds(
        (__attribute__((address_space(1))) void*)(g),
        (__attribute__((address_space(3))) void*)(l),
        16, 0, 0);
}

// ---------------- f32 -> f16 convert (x + weights) + RoPE tables ------------
__global__ __launch_bounds__(256) void cvt_all(
    const float* __restrict__ x,    _Float16* __restrict__ dx,
    const float* __restrict__ wqkv, _Float16* __restrict__ dq,
    const float* __restrict__ wo,   _Float16* __restrict__ dwo,
    const float* __restrict__ cosp, float* __restrict__ ctab,
    const float* __restrict__ sinp, float* __restrict__ stab)
{
    const int n0 = MROWS * HDIM / 8;  // 786432
    const int n1 = NQKV * HDIM / 8;   // 221184
    const int n2 = HDIM * HDIM / 8;   //  73728
    const int n3 = SDIM * 32 / 8;     //   8192 (compact tables, 8 f32/thread)
    int i = blockIdx.x * 256 + threadIdx.x;
    if (i >= n0 + n1 + n2) {
        int j = i - (n0 + n1 + n2);
        if (j >= n3) return;
        int s  = j >> 2;            // 0..2047
        int i0 = (j & 3) << 3;      // 0,8,16,24
        const float4* cs = (const float4*)(cosp + (long)s * HD + i0);
        const float4* sn = (const float4*)(sinp + (long)s * HD + i0);
        float4* dc = (float4*)(ctab + s * 32 + i0);
        float4* dsn = (float4*)(stab + s * 32 + i0);
        dc[0] = cs[0];  dc[1] = cs[1];
        dsn[0] = sn[0]; dsn[1] = sn[1];
        return;
    }
    const float* s; _Float16* d; int j;
    if (i < n0)            { s = x;    d = dx;  j = i; }
    else if (i < n0 + n1)  { s = wqkv; d = dq;  j = i - n0; }
    else                   { s = wo;   d = dwo; j = i - n0 - n1; }
    const float4* s4 = (const float4*)s + (long)j * 2;
    float4 a = s4[0], b = s4[1];
    f16x8 o;
    o[0] = (_Float16)a.x; o[1] = (_Float16)a.y;
    o[2] = (_Float16)a.z; o[3] = (_Float16)a.w;
    o[4] = (_Float16)b.x; o[5] = (_Float16)b.y;
    o[6] = (_Float16)b.z; o[7] = (_Float16)b.w;
    *((f16x8*)d + j) = o;
}

// ------------- QKV GEMM: 128x128 triple-buffered counted-vmcnt --------------
// (R12 engine, unchanged except compact-table epilogue)
__global__ __launch_bounds__(256) void gemm_qkv_t3(
    const _Float16* __restrict__ A,     // xh
    const _Float16* __restrict__ Bt,    // wqkvh
    const float* __restrict__ ctab,     // [S,32] f32, L2-resident
    const float* __restrict__ stab,
    _Float16* __restrict__ qh,
    _Float16* __restrict__ kh,
    _Float16* __restrict__ vh)
{
    const int K = HDIM;
    __shared__ __align__(16) _Float16 lsA[3][128 * 32];   // 8KB each
    __shared__ __align__(16) _Float16 lsB[3][128 * 32];

    const int nTn = NQKV >> 7;                // 18
    int nwg = gridDim.x;
    int bid = blockIdx.x;
    int cpx = nwg >> 3;                       // 1152 % 8 == 0
    int wg  = (bid & 7) * cpx + (bid >> 3);   // XCD-aware bijective swizzle
    int tm = wg / nTn, tn = wg % nTn;
    int m0 = tm << 7, n0 = tn << 7;

    int tid  = threadIdx.x;
    int lane = tid & 63;
    int w    = tid >> 6;
    int wr   = w >> 1, wc = w & 1;
    int l15  = lane & 15, lk = lane >> 4;

    f32x4 acc[4][4] = {};

    int srow = tid >> 2;                      // 0..63
    int lg   = (tid & 3) ^ ((tid >> 3) & 3);  // pre-swizzled source granule
    const _Float16* gA = A  + (long)(m0 + srow) * K + lg * 8;
    const _Float16* gB = Bt + (long)(n0 + srow) * K + lg * 8;

    auto STAGE = [&](int buf, int t) {
        gload16(gA + t * 32,            &lsA[buf][tid * 8]);
        gload16(gA + t * 32 + 64L * K,  &lsA[buf][tid * 8 + 2048]);
        gload16(gB + t * 32,            &lsB[buf][tid * 8]);
        gload16(gB + t * 32 + 64L * K,  &lsB[buf][tid * 8 + 2048]);
    };
    auto RD = [&](const _Float16* base, int rbase, int f) -> f16x8 {
        int r = rbase + f * 16 + l15;
        int pg = lk ^ ((r >> 1) & 3);
        return *(const f16x8*)&base[r * 32 + pg * 8];
    };

    const int NT = K >> 5;   // 24

    STAGE(0, 0);
    STAGE(1, 1);
    asm volatile("s_waitcnt vmcnt(4)" ::: "memory");   // tile 0 resident
    __builtin_amdgcn_s_barrier();

    int cur = 0;
    for (int t = 0; t < NT; ++t) {
        const _Float16* aC = lsA[cur];
        const _Float16* bC = lsB[cur];
        int stg = cur + 2; if (stg >= 3) stg -= 3;

        f16x8 af[4], bf[4];
#pragma unroll
        for (int mf = 0; mf < 4; ++mf) af[mf] = RD(aC, wr * 64, mf);
#pragma unroll
        for (int nf = 0; nf < 4; ++nf) bf[nf] = RD(bC, wc * 64, nf);
        if (t + 2 < NT) STAGE(stg, t + 2);

        __builtin_amdgcn_s_setprio(1);
#pragma unroll
        for (int mf = 0; mf < 4; ++mf)
#pragma unroll
            for (int nf = 0; nf < 4; ++nf)
                acc[mf][nf] = MFMA16(af[mf], bf[nf], acc[mf][nf]);
        __builtin_amdgcn_s_setprio(0);

        if (t + 1 < NT) {
            if (t + 2 < NT)
                asm volatile("s_waitcnt vmcnt(4)" ::: "memory"); // t+1 resident, t+2 in flight
            else
                asm volatile("s_waitcnt vmcnt(0)" ::: "memory");
            __builtin_amdgcn_s_barrier();
        }
        cur = cur + 1; if (cur == 3) cur = 0;
    }

    // ---- epilogue: RoPE (compact tables) + scatter ----
    int ht = (n0 >> 6) + wc;       // [0,36): t*12 + h
    int tq = ht / NH;
    int h  = ht - tq * NH;
    int b  = m0 >> 11;
    long base_bh = ((long)(b * NH + h)) * SDIM;
#pragma unroll
    for (int mf = 0; mf < 4; ++mf) {
#pragma unroll
        for (int j = 0; j < 4; ++j) {
            int gr = m0 + wr * 64 + mf * 16 + lk * 4 + j;
            int s  = gr & (SDIM - 1);
            if (tq == 2) {
#pragma unroll
                for (int nf = 0; nf < 4; ++nf) {
                    int d = nf * 16 + l15;
                    vh[(base_bh + s) * HD + d] = (_Float16)acc[mf][nf][j];
                }
            } else {
                float vals[4];
#pragma unroll
                for (int nf = 0; nf < 4; ++nf) vals[nf] = acc[mf][nf][j];
#pragma unroll
                for (int nf = 0; nf < 4; ++nf) {
                    int d  = nf * 16 + l15;
                    int di = ((nf & 1) << 4) + l15;        // d & 31
                    float cc = ctab[s * 32 + di];
                    float ss = stab[s * 32 + di];
                    float pv = (nf < 2) ? -vals[nf + 2] : vals[nf - 2];
                    float o  = vals[nf] * cc + pv * ss;
                    long oidx = (base_bh + s) * HD + d;
                    if (tq == 0) qh[oidx] = (_Float16)o;
                    else         kh[oidx] = (_Float16)o;
                }
            }
        }
    }
}

// --------------- out-proj GEMM: R12 kernel (verified best) ------------------
__global__ __launch_bounds__(256) void gemm_op8(
    const _Float16* __restrict__ A,
    const _Float16* __restrict__ Bt,
    float* __restrict__ C,
    int M, int N, int K)
{
    __shared__ __align__(16) _Float16 lsA[3][128 * 32];
    __shared__ __align__(16) _Float16 lsB[3][128 * 32];

    int nTn = N >> 7;
    int nwg = gridDim.x;
    int bid = blockIdx.x;
    int cpx = nwg >> 3;
    int wg  = (bid & 7) * cpx + (bid >> 3);
    int tm = wg / nTn, tn = wg % nTn;
    int m0 = tm << 7, n0 = tn << 7;

    int tid  = threadIdx.x;
    int lane = tid & 63;
    int w    = tid >> 6;
    int wr   = w >> 1, wc = w & 1;
    int l15  = lane & 15, lk = lane >> 4;

    f32x4 acc[4][4] = {};

    int srow = tid >> 2;
    int lg   = (tid & 3) ^ ((tid >> 3) & 3);
    const _Float16* gA = A  + (long)(m0 + srow) * K + lg * 8;
    const _Float16* gB = Bt + (long)(n0 + srow) * K + lg * 8;

    auto STAGE = [&](int buf, int t) {
        gload16(gA + t * 32,            &lsA[buf][tid * 8]);
        gload16(gA + t * 32 + 64L * K,  &lsA[buf][tid * 8 + 2048]);
        gload16(gB + t * 32,            &lsB[buf][tid * 8]);
        gload16(gB + t * 32 + 64L * K,  &lsB[buf][tid * 8 + 2048]);
    };
    auto RD = [&](const _Float16* base, int rbase, int f) -> f16x8 {
        int r = rbase + f * 16 + l15;
        int pg = lk ^ ((r >> 1) & 3);
        return *(const f16x8*)&base[r * 32 + pg * 8];
    };

    const int NT = K >> 5;   // 24

    STAGE(0, 0);
    STAGE(1, 1);
    asm volatile("s_waitcnt vmcnt(4)" ::: "memory");
    __builtin_amdgcn_s_barrier();

    int cur = 0;
    for (int t = 0; t < NT; ++t) {
        const _Float16* aC = lsA[cur];
        const _Float16* bC = lsB[cur];
        int stg = cur + 2; if (stg >= 3) stg -= 3;

        f16x8 af[4], bf[4];
#pragma unroll
        for (int mf = 0; mf < 4; ++mf) af[mf] = RD(aC, wr * 64, mf);
#pragma unroll
        for (int nf = 0; nf < 4; ++nf) bf[nf] = RD(bC, wc * 64, nf);
        if (t + 2 < NT) STAGE(stg, t + 2);

        __builtin_amdgcn_s_setprio(1);
#pragma unroll
        for (int mf = 0; mf < 4; ++mf)
#pragma unroll
            for (int nf = 0; nf < 4; ++nf)
                acc[mf][nf] = MFMA16(af[mf], bf[nf], acc[mf][nf]);
        __builtin_amdgcn_s_setprio(0);

        if (t + 1 < NT) {
            if (t + 2 < NT)
                asm volatile("s_waitcnt vmcnt(4)" ::: "memory");
            else
                asm volatile("s_waitcnt vmcnt(0)" ::: "memory");
            __builtin_amdgcn_s_barrier();
        }
        cur = cur + 1; if (cur == 3) cur = 0;
    }

#pragma unroll
    for (int mf = 0; mf < 4; ++mf)
#pragma unroll
        for (int nf = 0; nf < 4; ++nf)
#pragma unroll
            for (int j = 0; j < 4; ++j) {
                int gr = m0 + wr * 64 + mf * 16 + lk * 4 + j;
                int gc = n0 + wc * 64 + nf * 16 + l15;
                C[(long)gr * N + gc] = acc[mf][nf][j];
            }
}

// ---------------------------- MFMA attention --------------------------------
// Block = 4 waves = one (b,h, 64-query tile); key window = 192 keys.
#define SSTR 200
#define PSTR 200
__global__ __launch_bounds__(256) void attn_mfma(
    const _Float16* __restrict__ qh,
    const _Float16* __restrict__ kh,
    const _Float16* __restrict__ vh,
    _Float16* __restrict__ yh)
{
    __shared__ __align__(16) _Float16 lsVT[64 * SSTR];
    __shared__ __align__(16) _Float16 lsP [64 * PSTR];

    int bid = blockIdx.x;
    int qt  = bid & 31;
    int bh  = bid >> 5;
    int q0  = qt << 6;
    int k0  = q0 - 64;
    int tid = threadIdx.x;
    int lane = tid & 63;
    int w = tid >> 6;
    int l15 = lane & 15, lg = lane >> 4;

    const _Float16* Qb = qh + (long)bh * SDIM * HD;
    const _Float16* Kb = kh + (long)bh * SDIM * HD;
    const _Float16* Vb = vh + (long)bh * SDIM * HD;

#pragma unroll
    for (int c = 0; c < 3; ++c) {
        int rk = c * 64 + lane;
        int s  = k0 + rk;
        s = s < 0 ? 0 : (s >= SDIM ? SDIM - 1 : s);
        const f16x8* vr = (const f16x8*)(Vb + (long)s * HD + w * 16);
        f16x8 v0 = vr[0], v1 = vr[1];
#pragma unroll
        for (int e = 0; e < 8; ++e) {
            lsVT[(w * 16 + e)     * SSTR + rk] = v0[e];
            lsVT[(w * 16 + 8 + e) * SSTR + rk] = v1[e];
        }
    }

    int qrow = q0 + w * 16 + l15;
    const f16x8* qp = (const f16x8*)(Qb + (long)qrow * HD + lg * 8);
    f16x8 qa0 = qp[0];
    f16x8 qa1 = qp[4];

    float sums[4] = {0.f, 0.f, 0.f, 0.f};
    int iqb = w * 16 + lg * 4;
#pragma unroll 4
    for (int kt = 0; kt < 12; ++kt) {
        int krow = k0 + kt * 16 + l15;
        int kcl = krow < 0 ? 0 : (krow >= SDIM ? SDIM - 1 : krow);
        const f16x8* kp = (const f16x8*)(Kb + (long)kcl * HD + lg * 8);
        f16x8 kb0 = kp[0], kb1 = kp[4];
        f32x4 acc = {0.f, 0.f, 0.f, 0.f};
        acc = MFMA16(qa0, kb0, acc);
        acc = MFMA16(qa1, kb1, acc);
        int jk = kt * 16 + l15;
        bool kin = (krow >= 0) && (krow < SDIM);
#pragma unroll
        for (int j = 0; j < 4; ++j) {
            int i = iqb + j;
            bool valid = kin && (jk >= i) && (jk <= i + 128);
            float p = valid ? __expf(acc[j] * 0.125f) : 0.f;
            sums[j] += p;
            lsP[(w * 16 + lg * 4 + j) * PSTR + jk] = (_Float16)p;
        }
    }

#pragma unroll
    for (int m = 1; m < 16; m <<= 1) {
#pragma unroll
        for (int j = 0; j < 4; ++j)
            sums[j] += __shfl_xor(sums[j], m, 64);
    }
    float inv[4];
#pragma unroll
    for (int j = 0; j < 4; ++j) inv[j] = 1.f / sums[j];

    __syncthreads();

    f32x4 accy[4] = {};
    const _Float16* prow = &lsP[(w * 16 + l15) * PSTR + lg * 8];
#pragma unroll
    for (int kc = 0; kc < 6; ++kc) {
        f16x8 pa = *(const f16x8*)(prow + kc * 32);
#pragma unroll
        for (int dt = 0; dt < 4; ++dt) {
            f16x8 vb = *(const f16x8*)&lsVT[(dt * 16 + l15) * SSTR + kc * 32 + lg * 8];
            accy[dt] = MFMA16(pa, vb, accy[dt]);
        }
    }

    int b = bh / NH, h = bh - (bh / NH) * NH;
    long outbase = ((long)b * SDIM) * HDIM + (long)h * HD;
#pragma unroll
    for (int dt = 0; dt < 4; ++dt) {
#pragma unroll
        for (int j = 0; j < 4; ++j) {
            int srow = q0 + w * 16 + lg * 4 + j;
            yh[outbase + (long)srow * HDIM + dt * 16 + l15] =
                (_Float16)(accy[dt][j] * inv[j]);
        }
    }
}

// ---------------------------------------------------------------------------
extern "C" void kernel_launch(void* const* d_in, const int* in_sizes, int n_in,
                              void* d_out, int out_size, void* d_ws, size_t ws_size,
                              hipStream_t stream)
{
    const float* x    = (const float*)d_in[0];
    const float* cosp = (const float*)d_in[1];
    const float* sinp = (const float*)d_in[2];
    const float* Wqkv = (const float*)d_in[3];
    const float* Wo   = (const float*)d_in[4];
    float* out = (float*)d_out;

    char* ws = (char*)d_ws;
    _Float16* xh    = (_Float16*)(ws);                    // 12,582,912
    _Float16* wqkvh = (_Float16*)(ws + 12582912);         //  3,538,944
    _Float16* woh   = (_Float16*)(ws + 16121856);         //  1,179,648
    _Float16* qh    = (_Float16*)(ws + 17301504);         // 12,582,912
    _Float16* kh    = (_Float16*)(ws + 29884416);         // 12,582,912
    _Float16* vh    = (_Float16*)(ws + 42467328);         // 12,582,912
    _Float16* yh    = (_Float16*)(ws + 55050240);         // 12,582,912
    float*    ctab  = (float*)   (ws + 67633152);         //    262,144
    float*    stab  = (float*)   (ws + 67895296);         //    262,144 -> 68,157,440

    // 1) convert x + weights to f16; extract compact [S,32] RoPE tables
    {
        int nthr = MROWS * HDIM / 8 + NQKV * HDIM / 8 + HDIM * HDIM / 8
                 + SDIM * 32 / 8;
        cvt_all<<<(nthr + 255) / 256, 256, 0, stream>>>(
            x, xh, Wqkv, wqkvh, Wo, woh, cosp, ctab, sinp, stab);
    }

    // 2) QKV gemm: 128x128 triple-buffered counted-vmcnt, fused RoPE+scatter
    {
        dim3 grid((MROWS / 128) * (NQKV / 128));   // 1152
        gemm_qkv_t3<<<grid, 256, 0, stream>>>(xh, wqkvh, ctab, stab, qh, kh, vh);
    }

    // 3) sliding-window MFMA attention
    {
        dim3 grid(BDIM * NH * (SDIM / 64));        // 1536
        attn_mfma<<<grid, 256, 0, stream>>>(qh, kh, vh, yh);
    }

    // 4) output projection (R12 kernel)
    {
        dim3 grid((MROWS / 128) * (HDIM / 128));   // 384
        gemm_op8<<<grid, 256, 0, stream>>>(yh, woh, out, MROWS, HDIM, HDIM);
    }
}

// Round 16
// 100.904 us; speedup vs baseline: 1.1059x; 1.0380x over previous
//
#include <hip/hip_runtime.h>

// ---------------------------------------------------------------------------
// ModernBertAttention: x[4,2048,768] -> QKV gemm(+RoPE) -> sliding-window
// MFMA attention (window=64) -> out-proj gemm.  out f32 [4,2048,768].
// Base = R15 (measured best 104.7us). Change: attention band-skip -- each
// wave computes only the kt/kc tiles intersecting its 16 query rows' valid
// band (10/12 QK tiles, 5/6 PV granules; exact cover, bit-equivalent).
// ---------------------------------------------------------------------------

typedef __attribute__((ext_vector_type(8))) _Float16 f16x8;
typedef __attribute__((ext_vector_type(4))) float    f32x4;

#define BDIM 4
#define SDIM 2048
#define HDIM 768
#define NH   12
#define HD   64
#define NQKV 2304   // 3*HDIM
#define MROWS 8192  // B*S

#define MFMA16(a, b, c) __builtin_amdgcn_mfma_f32_16x16x32_f16(a, b, c, 0, 0, 0)

// ---------------------------------------------------------------------------
__device__ __forceinline__ void gload16(const void* g, void* l) {
    __builtin_amdgcn_global_load_lds(
        (__attribute__((address_space(1))) void*)(g),
        (__attribute__((address_space(3))) void*)(l),
        16, 0, 0);
}

// ---------------- f32 -> f16 convert (x + weights) + RoPE tables ------------
__global__ __launch_bounds__(256) void cvt_all(
    const float* __restrict__ x,    _Float16* __restrict__ dx,
    const float* __restrict__ wqkv, _Float16* __restrict__ dq,
    const float* __restrict__ wo,   _Float16* __restrict__ dwo,
    const float* __restrict__ cosp, float* __restrict__ ctab,
    const float* __restrict__ sinp, float* __restrict__ stab)
{
    const int n0 = MROWS * HDIM / 8;  // 786432
    const int n1 = NQKV * HDIM / 8;   // 221184
    const int n2 = HDIM * HDIM / 8;   //  73728
    const int n3 = SDIM * 32 / 8;     //   8192 (compact tables, 8 f32/thread)
    int i = blockIdx.x * 256 + threadIdx.x;
    if (i >= n0 + n1 + n2) {
        int j = i - (n0 + n1 + n2);
        if (j >= n3) return;
        int s  = j >> 2;            // 0..2047
        int i0 = (j & 3) << 3;      // 0,8,16,24
        const float4* cs = (const float4*)(cosp + (long)s * HD + i0);
        const float4* sn = (const float4*)(sinp + (long)s * HD + i0);
        float4* dc = (float4*)(ctab + s * 32 + i0);
        float4* dsn = (float4*)(stab + s * 32 + i0);
        dc[0] = cs[0];  dc[1] = cs[1];
        dsn[0] = sn[0]; dsn[1] = sn[1];
        return;
    }
    const float* s; _Float16* d; int j;
    if (i < n0)            { s = x;    d = dx;  j = i; }
    else if (i < n0 + n1)  { s = wqkv; d = dq;  j = i - n0; }
    else                   { s = wo;   d = dwo; j = i - n0 - n1; }
    const float4* s4 = (const float4*)s + (long)j * 2;
    float4 a = s4[0], b = s4[1];
    f16x8 o;
    o[0] = (_Float16)a.x; o[1] = (_Float16)a.y;
    o[2] = (_Float16)a.z; o[3] = (_Float16)a.w;
    o[4] = (_Float16)b.x; o[5] = (_Float16)b.y;
    o[6] = (_Float16)b.z; o[7] = (_Float16)b.w;
    *((f16x8*)d + j) = o;
}

// ------------- QKV GEMM: 128x128 triple-buffered counted-vmcnt --------------
// (R15 kernel, unchanged -- 52us measured, compact-table epilogue)
__global__ __launch_bounds__(256) void gemm_qkv_t3(
    const _Float16* __restrict__ A,     // xh
    const _Float16* __restrict__ Bt,    // wqkvh
    const float* __restrict__ ctab,     // [S,32] f32, L2-resident
    const float* __restrict__ stab,
    _Float16* __restrict__ qh,
    _Float16* __restrict__ kh,
    _Float16* __restrict__ vh)
{
    const int K = HDIM;
    __shared__ __align__(16) _Float16 lsA[3][128 * 32];   // 8KB each
    __shared__ __align__(16) _Float16 lsB[3][128 * 32];

    const int nTn = NQKV >> 7;                // 18
    int nwg = gridDim.x;
    int bid = blockIdx.x;
    int cpx = nwg >> 3;                       // 1152 % 8 == 0
    int wg  = (bid & 7) * cpx + (bid >> 3);   // XCD-aware bijective swizzle
    int tm = wg / nTn, tn = wg % nTn;
    int m0 = tm << 7, n0 = tn << 7;

    int tid  = threadIdx.x;
    int lane = tid & 63;
    int w    = tid >> 6;
    int wr   = w >> 1, wc = w & 1;
    int l15  = lane & 15, lk = lane >> 4;

    f32x4 acc[4][4] = {};

    int srow = tid >> 2;                      // 0..63
    int lg   = (tid & 3) ^ ((tid >> 3) & 3);  // pre-swizzled source granule
    const _Float16* gA = A  + (long)(m0 + srow) * K + lg * 8;
    const _Float16* gB = Bt + (long)(n0 + srow) * K + lg * 8;

    auto STAGE = [&](int buf, int t) {
        gload16(gA + t * 32,            &lsA[buf][tid * 8]);
        gload16(gA + t * 32 + 64L * K,  &lsA[buf][tid * 8 + 2048]);
        gload16(gB + t * 32,            &lsB[buf][tid * 8]);
        gload16(gB + t * 32 + 64L * K,  &lsB[buf][tid * 8 + 2048]);
    };
    auto RD = [&](const _Float16* base, int rbase, int f) -> f16x8 {
        int r = rbase + f * 16 + l15;
        int pg = lk ^ ((r >> 1) & 3);
        return *(const f16x8*)&base[r * 32 + pg * 8];
    };

    const int NT = K >> 5;   // 24

    STAGE(0, 0);
    STAGE(1, 1);
    asm volatile("s_waitcnt vmcnt(4)" ::: "memory");   // tile 0 resident
    __builtin_amdgcn_s_barrier();

    int cur = 0;
    for (int t = 0; t < NT; ++t) {
        const _Float16* aC = lsA[cur];
        const _Float16* bC = lsB[cur];
        int stg = cur + 2; if (stg >= 3) stg -= 3;

        f16x8 af[4], bf[4];
#pragma unroll
        for (int mf = 0; mf < 4; ++mf) af[mf] = RD(aC, wr * 64, mf);
#pragma unroll
        for (int nf = 0; nf < 4; ++nf) bf[nf] = RD(bC, wc * 64, nf);
        if (t + 2 < NT) STAGE(stg, t + 2);

        __builtin_amdgcn_s_setprio(1);
#pragma unroll
        for (int mf = 0; mf < 4; ++mf)
#pragma unroll
            for (int nf = 0; nf < 4; ++nf)
                acc[mf][nf] = MFMA16(af[mf], bf[nf], acc[mf][nf]);
        __builtin_amdgcn_s_setprio(0);

        if (t + 1 < NT) {
            if (t + 2 < NT)
                asm volatile("s_waitcnt vmcnt(4)" ::: "memory"); // t+1 resident, t+2 in flight
            else
                asm volatile("s_waitcnt vmcnt(0)" ::: "memory");
            __builtin_amdgcn_s_barrier();
        }
        cur = cur + 1; if (cur == 3) cur = 0;
    }

    // ---- epilogue: RoPE (compact tables) + scatter ----
    int ht = (n0 >> 6) + wc;       // [0,36): t*12 + h
    int tq = ht / NH;
    int h  = ht - tq * NH;
    int b  = m0 >> 11;
    long base_bh = ((long)(b * NH + h)) * SDIM;
#pragma unroll
    for (int mf = 0; mf < 4; ++mf) {
#pragma unroll
        for (int j = 0; j < 4; ++j) {
            int gr = m0 + wr * 64 + mf * 16 + lk * 4 + j;
            int s  = gr & (SDIM - 1);
            if (tq == 2) {
#pragma unroll
                for (int nf = 0; nf < 4; ++nf) {
                    int d = nf * 16 + l15;
                    vh[(base_bh + s) * HD + d] = (_Float16)acc[mf][nf][j];
                }
            } else {
                float vals[4];
#pragma unroll
                for (int nf = 0; nf < 4; ++nf) vals[nf] = acc[mf][nf][j];
#pragma unroll
                for (int nf = 0; nf < 4; ++nf) {
                    int d  = nf * 16 + l15;
                    int di = ((nf & 1) << 4) + l15;        // d & 31
                    float cc = ctab[s * 32 + di];
                    float ss = stab[s * 32 + di];
                    float pv = (nf < 2) ? -vals[nf + 2] : vals[nf - 2];
                    float o  = vals[nf] * cc + pv * ss;
                    long oidx = (base_bh + s) * HD + d;
                    if (tq == 0) qh[oidx] = (_Float16)o;
                    else         kh[oidx] = (_Float16)o;
                }
            }
        }
    }
}

// --------------- out-proj GEMM: R12 kernel (verified best) ------------------
__global__ __launch_bounds__(256) void gemm_op8(
    const _Float16* __restrict__ A,
    const _Float16* __restrict__ Bt,
    float* __restrict__ C,
    int M, int N, int K)
{
    __shared__ __align__(16) _Float16 lsA[3][128 * 32];
    __shared__ __align__(16) _Float16 lsB[3][128 * 32];

    int nTn = N >> 7;
    int nwg = gridDim.x;
    int bid = blockIdx.x;
    int cpx = nwg >> 3;
    int wg  = (bid & 7) * cpx + (bid >> 3);
    int tm = wg / nTn, tn = wg % nTn;
    int m0 = tm << 7, n0 = tn << 7;

    int tid  = threadIdx.x;
    int lane = tid & 63;
    int w    = tid >> 6;
    int wr   = w >> 1, wc = w & 1;
    int l15  = lane & 15, lk = lane >> 4;

    f32x4 acc[4][4] = {};

    int srow = tid >> 2;
    int lg   = (tid & 3) ^ ((tid >> 3) & 3);
    const _Float16* gA = A  + (long)(m0 + srow) * K + lg * 8;
    const _Float16* gB = Bt + (long)(n0 + srow) * K + lg * 8;

    auto STAGE = [&](int buf, int t) {
        gload16(gA + t * 32,            &lsA[buf][tid * 8]);
        gload16(gA + t * 32 + 64L * K,  &lsA[buf][tid * 8 + 2048]);
        gload16(gB + t * 32,            &lsB[buf][tid * 8]);
        gload16(gB + t * 32 + 64L * K,  &lsB[buf][tid * 8 + 2048]);
    };
    auto RD = [&](const _Float16* base, int rbase, int f) -> f16x8 {
        int r = rbase + f * 16 + l15;
        int pg = lk ^ ((r >> 1) & 3);
        return *(const f16x8*)&base[r * 32 + pg * 8];
    };

    const int NT = K >> 5;   // 24

    STAGE(0, 0);
    STAGE(1, 1);
    asm volatile("s_waitcnt vmcnt(4)" ::: "memory");
    __builtin_amdgcn_s_barrier();

    int cur = 0;
    for (int t = 0; t < NT; ++t) {
        const _Float16* aC = lsA[cur];
        const _Float16* bC = lsB[cur];
        int stg = cur + 2; if (stg >= 3) stg -= 3;

        f16x8 af[4], bf[4];
#pragma unroll
        for (int mf = 0; mf < 4; ++mf) af[mf] = RD(aC, wr * 64, mf);
#pragma unroll
        for (int nf = 0; nf < 4; ++nf) bf[nf] = RD(bC, wc * 64, nf);
        if (t + 2 < NT) STAGE(stg, t + 2);

        __builtin_amdgcn_s_setprio(1);
#pragma unroll
        for (int mf = 0; mf < 4; ++mf)
#pragma unroll
            for (int nf = 0; nf < 4; ++nf)
                acc[mf][nf] = MFMA16(af[mf], bf[nf], acc[mf][nf]);
        __builtin_amdgcn_s_setprio(0);

        if (t + 1 < NT) {
            if (t + 2 < NT)
                asm volatile("s_waitcnt vmcnt(4)" ::: "memory");
            else
                asm volatile("s_waitcnt vmcnt(0)" ::: "memory");
            __builtin_amdgcn_s_barrier();
        }
        cur = cur + 1; if (cur == 3) cur = 0;
    }

#pragma unroll
    for (int mf = 0; mf < 4; ++mf)
#pragma unroll
        for (int nf = 0; nf < 4; ++nf)
#pragma unroll
            for (int j = 0; j < 4; ++j) {
                int gr = m0 + wr * 64 + mf * 16 + lk * 4 + j;
                int gc = n0 + wc * 64 + nf * 16 + l15;
                C[(long)gr * N + gc] = acc[mf][nf][j];
            }
}

// ---------------------------- MFMA attention --------------------------------
// Block = 4 waves = one (b,h, 64-query tile); key window = 192 keys.
// Band-skip: wave w's 16 query rows have valid keys only in
// jk in [16w, 16w+143]; the P region PV reads is granules [w>>1, w>>1+4]
// = cols [32*(w>>1), 32*(w>>1)+159], exactly covered by kt in
// [w&~1, (w&~1)+9]. -> 10/12 QK tiles, 5/6 PV granules, bit-equivalent.
#define SSTR 200
#define PSTR 200
__global__ __launch_bounds__(256) void attn_mfma(
    const _Float16* __restrict__ qh,
    const _Float16* __restrict__ kh,
    const _Float16* __restrict__ vh,
    _Float16* __restrict__ yh)
{
    __shared__ __align__(16) _Float16 lsVT[64 * SSTR];
    __shared__ __align__(16) _Float16 lsP [64 * PSTR];

    int bid = blockIdx.x;
    int qt  = bid & 31;
    int bh  = bid >> 5;
    int q0  = qt << 6;
    int k0  = q0 - 64;
    int tid = threadIdx.x;
    int lane = tid & 63;
    int w = tid >> 6;
    int l15 = lane & 15, lg = lane >> 4;

    const _Float16* Qb = qh + (long)bh * SDIM * HD;
    const _Float16* Kb = kh + (long)bh * SDIM * HD;
    const _Float16* Vb = vh + (long)bh * SDIM * HD;

#pragma unroll
    for (int c = 0; c < 3; ++c) {
        int rk = c * 64 + lane;
        int s  = k0 + rk;
        s = s < 0 ? 0 : (s >= SDIM ? SDIM - 1 : s);
        const f16x8* vr = (const f16x8*)(Vb + (long)s * HD + w * 16);
        f16x8 v0 = vr[0], v1 = vr[1];
#pragma unroll
        for (int e = 0; e < 8; ++e) {
            lsVT[(w * 16 + e)     * SSTR + rk] = v0[e];
            lsVT[(w * 16 + 8 + e) * SSTR + rk] = v1[e];
        }
    }

    int qrow = q0 + w * 16 + l15;
    const f16x8* qp = (const f16x8*)(Qb + (long)qrow * HD + lg * 8);
    f16x8 qa0 = qp[0];
    f16x8 qa1 = qp[4];

    float sums[4] = {0.f, 0.f, 0.f, 0.f};
    int iqb = w * 16 + lg * 4;
    int kt0 = w & ~1;                 // first kt tile this wave needs
#pragma unroll 5
    for (int tt = 0; tt < 10; ++tt) {
        int kt = kt0 + tt;
        int krow = k0 + kt * 16 + l15;
        int kcl = krow < 0 ? 0 : (krow >= SDIM ? SDIM - 1 : krow);
        const f16x8* kp = (const f16x8*)(Kb + (long)kcl * HD + lg * 8);
        f16x8 kb0 = kp[0], kb1 = kp[4];
        f32x4 acc = {0.f, 0.f, 0.f, 0.f};
        acc = MFMA16(qa0, kb0, acc);
        acc = MFMA16(qa1, kb1, acc);
        int jk = kt * 16 + l15;
        bool kin = (krow >= 0) && (krow < SDIM);
#pragma unroll
        for (int j = 0; j < 4; ++j) {
            int i = iqb + j;
            bool valid = kin && (jk >= i) && (jk <= i + 128);
            float p = valid ? __expf(acc[j] * 0.125f) : 0.f;
            sums[j] += p;
            lsP[(w * 16 + lg * 4 + j) * PSTR + jk] = (_Float16)p;
        }
    }

#pragma unroll
    for (int m = 1; m < 16; m <<= 1) {
#pragma unroll
        for (int j = 0; j < 4; ++j)
            sums[j] += __shfl_xor(sums[j], m, 64);
    }
    float inv[4];
#pragma unroll
    for (int j = 0; j < 4; ++j) inv[j] = 1.f / sums[j];

    __syncthreads();

    f32x4 accy[4] = {};
    const _Float16* prow = &lsP[(w * 16 + l15) * PSTR + lg * 8];
    int kc0 = w >> 1;                 // first PV granule this wave needs
#pragma unroll
    for (int c5 = 0; c5 < 5; ++c5) {
        int kc = kc0 + c5;
        f16x8 pa = *(const f16x8*)(prow + kc * 32);
#pragma unroll
        for (int dt = 0; dt < 4; ++dt) {
            f16x8 vb = *(const f16x8*)&lsVT[(dt * 16 + l15) * SSTR + kc * 32 + lg * 8];
            accy[dt] = MFMA16(pa, vb, accy[dt]);
        }
    }

    int b = bh / NH, h = bh - (bh / NH) * NH;
    long outbase = ((long)b * SDIM) * HDIM + (long)h * HD;
#pragma unroll
    for (int dt = 0; dt < 4; ++dt) {
#pragma unroll
        for (int j = 0; j < 4; ++j) {
            int srow = q0 + w * 16 + lg * 4 + j;
            yh[outbase + (long)srow * HDIM + dt * 16 + l15] =
                (_Float16)(accy[dt][j] * inv[j]);
        }
    }
}

// ---------------------------------------------------------------------------
extern "C" void kernel_launch(void* const* d_in, const int* in_sizes, int n_in,
                              void* d_out, int out_size, void* d_ws, size_t ws_size,
                              hipStream_t stream)
{
    const float* x    = (const float*)d_in[0];
    const float* cosp = (const float*)d_in[1];
    const float* sinp = (const float*)d_in[2];
    const float* Wqkv = (const float*)d_in[3];
    const float* Wo   = (const float*)d_in[4];
    float* out = (float*)d_out;

    char* ws = (char*)d_ws;
    _Float16* xh    = (_Float16*)(ws);                    // 12,582,912
    _Float16* wqkvh = (_Float16*)(ws + 12582912);         //  3,538,944
    _Float16* woh   = (_Float16*)(ws + 16121856);         //  1,179,648
    _Float16* qh    = (_Float16*)(ws + 17301504);         // 12,582,912
    _Float16* kh    = (_Float16*)(ws + 29884416);         // 12,582,912
    _Float16* vh    = (_Float16*)(ws + 42467328);         // 12,582,912
    _Float16* yh    = (_Float16*)(ws + 55050240);         // 12,582,912
    float*    ctab  = (float*)   (ws + 67633152);         //    262,144
    float*    stab  = (float*)   (ws + 67895296);         //    262,144 -> 68,157,440

    // 1) convert x + weights to f16; extract compact [S,32] RoPE tables
    {
        int nthr = MROWS * HDIM / 8 + NQKV * HDIM / 8 + HDIM * HDIM / 8
                 + SDIM * 32 / 8;
        cvt_all<<<(nthr + 255) / 256, 256, 0, stream>>>(
            x, xh, Wqkv, wqkvh, Wo, woh, cosp, ctab, sinp, stab);
    }

    // 2) QKV gemm: 128x128 triple-buffered counted-vmcnt, fused RoPE+scatter
    {
        dim3 grid((MROWS / 128) * (NQKV / 128));   // 1152
        gemm_qkv_t3<<<grid, 256, 0, stream>>>(xh, wqkvh, ctab, stab, qh, kh, vh);
    }

    // 3) sliding-window MFMA attention (band-skip)
    {
        dim3 grid(BDIM * NH * (SDIM / 64));        // 1536
        attn_mfma<<<grid, 256, 0, stream>>>(qh, kh, vh, yh);
    }

    // 4) output projection (R12 kernel)
    {
        dim3 grid((MROWS / 128) * (HDIM / 128));   // 384
        gemm_op8<<<grid, 256, 0, stream>>>(yh, woh, out, MROWS, HDIM, HDIM);
    }
}